// Round 4
// baseline (609.421 us; speedup 1.0000x reference)
//
#include <hip/hip_runtime.h>

// out = x + Ax + A^2 x + A^3 x
// COO -> CSR via 2-level bucketed counting sort; pull gather SpMM with fp16 operand.
// N=100000, D=100, E=1600000, layer_num=3 (fixed by setup_inputs)

#define NODES 100000
#define DIM 100
#define DIM4 25                       // 4-feature chunks per row
#define SCAN_BLK 256
#define NBLK ((NODES + SCAN_BLK - 1) / SCAN_BLK)   // 391
#define NPAD (NBLK * SCAN_BLK)                     // 100096
#define BSHIFT 5
#define NBUCKETS ((NODES + 31) / 32)               // 3125 buckets of 32 rows

typedef _Float16 half4_t __attribute__((ext_vector_type(4)));

__global__ void hist_kernel(const int* __restrict__ rows, int* __restrict__ counts, int E) {
    int e = blockIdx.x * blockDim.x + threadIdx.x;
    if (e < E) atomicAdd(&counts[rows[e]], 1);
}

__global__ void scan1_kernel(int* __restrict__ data, int* __restrict__ blocksums, int n) {
    __shared__ int s[SCAN_BLK];
    int gid = blockIdx.x * SCAN_BLK + threadIdx.x;
    int v = (gid < n) ? data[gid] : 0;
    s[threadIdx.x] = v;
    __syncthreads();
    for (int off = 1; off < SCAN_BLK; off <<= 1) {
        int t = (threadIdx.x >= off) ? s[threadIdx.x - off] : 0;
        __syncthreads();
        s[threadIdx.x] += t;
        __syncthreads();
    }
    data[gid] = s[threadIdx.x] - v;                 // exclusive
    if (threadIdx.x == SCAN_BLK - 1) blocksums[blockIdx.x] = s[SCAN_BLK - 1];
}

__global__ void scan2_kernel(int* __restrict__ bs, int nb) {
    __shared__ int s[512];
    int v = ((int)threadIdx.x < nb) ? bs[threadIdx.x] : 0;
    s[threadIdx.x] = v;
    __syncthreads();
    for (int off = 1; off < 512; off <<= 1) {
        int t = ((int)threadIdx.x >= off) ? s[threadIdx.x - off] : 0;
        __syncthreads();
        s[threadIdx.x] += t;
        __syncthreads();
    }
    if ((int)threadIdx.x < nb) bs[threadIdx.x] = s[threadIdx.x] - v;
}

// finalize scan; init row cursor and coarse-bucket append cursor
__global__ void scan3_kernel(int* __restrict__ data, int* __restrict__ cursor,
                             int* __restrict__ bktCur, const int* __restrict__ bs) {
    int gid = blockIdx.x * SCAN_BLK + threadIdx.x;
    int v = data[gid] + bs[blockIdx.x];
    data[gid] = v;
    cursor[gid] = v;
    if ((gid & 31) == 0 && (gid >> BSHIFT) < NBUCKETS) bktCur[gid >> BSHIFT] = v;
}

// pass 1: append edges into coarse buckets (3125 append streams -> L2-friendly writes)
__global__ void pass1_kernel(const int* __restrict__ rows, const int* __restrict__ cols,
                             const float* __restrict__ vals,
                             int* __restrict__ bktCur, int4* __restrict__ staging, int E) {
    int e = blockIdx.x * blockDim.x + threadIdx.x;
    if (e < E) {
        int r = rows[e];
        int c = cols[e];
        int v = __float_as_int(vals[e]);
        int pos = atomicAdd(&bktCur[r >> BSHIFT], 1);
        staging[pos] = make_int4(r, c, v, 0);
    }
}

// pass 2: one block per bucket; scatter within the bucket's ~4KB CSR window.
// Row cursors are bucket-exclusive -> no cross-XCD bouncing.
__global__ void pass2_kernel(const int* __restrict__ rowstart, int* __restrict__ cursor,
                             const int4* __restrict__ staging, int2* __restrict__ csr) {
    int b = blockIdx.x;
    int s = rowstart[b << BSHIFT];
    int e = rowstart[(b + 1) << BSHIFT];
    for (int i = s + threadIdx.x; i < e; i += blockDim.x) {
        int4 rec = staging[i];
        int pos = atomicAdd(&cursor[rec.x], 1);
        csr[pos] = make_int2(rec.y, rec.z);
    }
}

// fp32 [N*D] -> fp16 [N*D]
__global__ void cvt_kernel(const float4* __restrict__ src, half4_t* __restrict__ dst, int n4) {
    int i = blockIdx.x * blockDim.x + threadIdx.x;
    if (i < n4) {
        float4 f = src[i];
        half4_t h;
        h.x = (_Float16)f.x; h.y = (_Float16)f.y; h.z = (_Float16)f.z; h.w = (_Float16)f.w;
        dst[i] = h;
    }
}

// pull SpMM: 32 lanes per row, lanes 0..24 each own 4 features (8 B fp16 chunk).
__global__ void gather_kernel(const int* __restrict__ rowstart,
                              const int2* __restrict__ csr,
                              const half4_t* __restrict__ x,
                              half4_t* __restrict__ h) {
    int gid = blockIdx.x * blockDim.x + threadIdx.x;
    int row  = gid >> 5;
    int lane = gid & 31;
    if (row >= NODES || lane >= DIM4) return;
    int start = rowstart[row];
    int end   = rowstart[row + 1];
    float4 acc = make_float4(0.f, 0.f, 0.f, 0.f);
    int i = start;
    for (; i + 1 < end; i += 2) {                   // 2x unroll: two gathers in flight
        int2 r0 = csr[i];
        int2 r1 = csr[i + 1];
        half4_t a = x[(size_t)r0.x * DIM4 + lane];
        half4_t b = x[(size_t)r1.x * DIM4 + lane];
        float v0 = __int_as_float(r0.y);
        float v1 = __int_as_float(r1.y);
        acc.x += v0 * (float)a.x + v1 * (float)b.x;
        acc.y += v0 * (float)a.y + v1 * (float)b.y;
        acc.z += v0 * (float)a.z + v1 * (float)b.z;
        acc.w += v0 * (float)a.w + v1 * (float)b.w;
    }
    if (i < end) {
        int2 r0 = csr[i];
        half4_t a = x[(size_t)r0.x * DIM4 + lane];
        float v0 = __int_as_float(r0.y);
        acc.x += v0 * (float)a.x;
        acc.y += v0 * (float)a.y;
        acc.z += v0 * (float)a.z;
        acc.w += v0 * (float)a.w;
    }
    half4_t hv;
    hv.x = (_Float16)acc.x; hv.y = (_Float16)acc.y;
    hv.z = (_Float16)acc.z; hv.w = (_Float16)acc.w;
    h[(size_t)row * DIM4 + lane] = hv;
}

// out = emb + h1 + h2 + h3
__global__ void combine_kernel(const float4* __restrict__ emb,
                               const half4_t* __restrict__ h1,
                               const half4_t* __restrict__ h2,
                               const half4_t* __restrict__ h3,
                               float4* __restrict__ out, int n4) {
    int i = blockIdx.x * blockDim.x + threadIdx.x;
    if (i < n4) {
        float4 o = emb[i];
        half4_t a = h1[i], b = h2[i], c = h3[i];
        o.x += (float)a.x + (float)b.x + (float)c.x;
        o.y += (float)a.y + (float)b.y + (float)c.y;
        o.z += (float)a.z + (float)b.z + (float)c.z;
        o.w += (float)a.w + (float)b.w + (float)c.w;
        out[i] = o;
    }
}

extern "C" void kernel_launch(void* const* d_in, const int* in_sizes, int n_in,
                              void* d_out, int out_size, void* d_ws, size_t ws_size,
                              hipStream_t stream) {
    const float* emb  = (const float*)d_in[0];
    const int*   rows = (const int*)  d_in[1];
    const int*   cols = (const int*)  d_in[2];
    const float* vals = (const float*)d_in[3];
    const int E = in_sizes[1];

    const size_t nd   = (size_t)NODES * DIM;               // 10M elements
    const size_t nd_h = nd * sizeof(_Float16);             // 20 MB

    char* w = (char*)d_ws;
    half4_t* x0       = (half4_t*)w;  w += nd_h;
    half4_t* h1       = (half4_t*)w;  w += nd_h;
    half4_t* h2       = (half4_t*)w;  w += nd_h;           // ┐ staging aliases h2+h3
    half4_t* h3       = (half4_t*)w;  w += nd_h;           // ┘ (dead after pass2)
    int4*    staging  = (int4*)h2;                         // 25.6 MB <= 40 MB
    int2*    csr      = (int2*)   w;  w += (size_t)E * sizeof(int2);   // 12.8 MB
    int*     rowstart = (int*)    w;  w += (size_t)NPAD * sizeof(int);
    int*     cursor   = (int*)    w;  w += (size_t)NPAD * sizeof(int);
    int*     bktCur   = (int*)    w;  w += 3200 * sizeof(int);
    int*     bsums    = (int*)    w;  w += 512 * sizeof(int);

    float4* out = (float4*)d_out;
    const int n4 = (int)(nd / 4);                          // 2.5M

    // ---- build CSR: hist -> scan -> bucket-append -> bucket-local scatter ----
    hipMemsetAsync(rowstart, 0, (size_t)NPAD * sizeof(int), stream);
    cvt_kernel<<<(n4 + 255) / 256, 256, 0, stream>>>((const float4*)emb, x0, n4);
    hist_kernel<<<(E + 255) / 256, 256, 0, stream>>>(rows, rowstart, E);
    scan1_kernel<<<NBLK, SCAN_BLK, 0, stream>>>(rowstart, bsums, NODES);
    scan2_kernel<<<1, 512, 0, stream>>>(bsums, NBLK);
    scan3_kernel<<<NBLK, SCAN_BLK, 0, stream>>>(rowstart, cursor, bktCur, bsums);
    pass1_kernel<<<(E + 255) / 256, 256, 0, stream>>>(rows, cols, vals, bktCur, staging, E);
    pass2_kernel<<<NBUCKETS, 256, 0, stream>>>(rowstart, cursor, staging, csr);

    // ---- 3 gather SpMM layers (hop outputs only), then one combine ----
    const long long threads = (long long)NODES * 32;
    dim3 gGrid((unsigned)((threads + 255) / 256)), gBlock(256);
    gather_kernel<<<gGrid, gBlock, 0, stream>>>(rowstart, csr, x0, h1);
    gather_kernel<<<gGrid, gBlock, 0, stream>>>(rowstart, csr, h1, h2);
    gather_kernel<<<gGrid, gBlock, 0, stream>>>(rowstart, csr, h2, h3);
    combine_kernel<<<(n4 + 255) / 256, 256, 0, stream>>>((const float4*)emb, h1, h2, h3, out, n4);
}

// Round 5
// 395.296 us; speedup vs baseline: 1.5417x; 1.5417x over previous
//
#include <hip/hip_runtime.h>

// out = x + Ax + A^2 x + A^3 x
// Build: block-privatized 2-level counting sort (coarse buckets of 256 rows) -> CSR.
// SpMM: pull gather, fp16 operand padded to 208 B rows, 13 x 16B loads per edge.
// N=100000, D=100, E=1600000, layer_num=3 (fixed by setup_inputs)

#define NODES 100000
#define DIM 100
#define DIM4 25                        // float4 chunks per compact row
#define CH 13                          // 16B fp16 chunks per padded row (104 halves)
#define BSHIFT 8
#define NBUCKETS ((NODES + 255) >> 8)  // 391 buckets of 256 rows
#define P1_BLOCKS 256

typedef _Float16 half4_t __attribute__((ext_vector_type(4)));
typedef _Float16 half8_t __attribute__((ext_vector_type(8)));

// fp32 compact [N][100] -> fp16 padded [N][104] (pad elements zeroed)
__global__ void cvt_pad_kernel(const float4* __restrict__ src, half4_t* __restrict__ dst) {
    int i = blockIdx.x * blockDim.x + threadIdx.x;   // over NODES*26 half4-chunks
    if (i >= NODES * 26) return;
    int row = i / 26, c = i - row * 26;
    half4_t h;
    if (c < 25) {
        float4 f = src[row * 25 + c];
        h.x = (_Float16)f.x; h.y = (_Float16)f.y; h.z = (_Float16)f.z; h.w = (_Float16)f.w;
    } else {
        h.x = (_Float16)0.f; h.y = (_Float16)0.f; h.z = (_Float16)0.f; h.w = (_Float16)0.f;
    }
    dst[row * 26 + c] = h;
}

// coarse-bucket histogram (LDS-privatized)
__global__ void bucket_hist_kernel(const int* __restrict__ rows, int* __restrict__ bktCount, int E) {
    __shared__ int h[NBUCKETS];
    for (int i = threadIdx.x; i < NBUCKETS; i += blockDim.x) h[i] = 0;
    __syncthreads();
    for (int e = blockIdx.x * blockDim.x + threadIdx.x; e < E; e += gridDim.x * blockDim.x)
        atomicAdd(&h[rows[e] >> BSHIFT], 1);
    __syncthreads();
    for (int i = threadIdx.x; i < NBUCKETS; i += blockDim.x)
        if (h[i]) atomicAdd(&bktCount[i], h[i]);
}

// single-block exclusive scan of 391 bucket counts -> bktStart[392], bktCur init
__global__ void bucket_scan_kernel(const int* __restrict__ bktCount,
                                   int* __restrict__ bktStart, int* __restrict__ bktCur) {
    __shared__ int s[512];
    int tid = threadIdx.x;
    int v = (tid < NBUCKETS) ? bktCount[tid] : 0;
    s[tid] = v;
    __syncthreads();
    for (int off = 1; off < 512; off <<= 1) {
        int t = (tid >= off) ? s[tid - off] : 0;
        __syncthreads();
        s[tid] += t;
        __syncthreads();
    }
    int excl = s[tid] - v;
    if (tid <= NBUCKETS) bktStart[tid] = excl;   // tid==NBUCKETS -> total == E
    if (tid < NBUCKETS)  bktCur[tid]  = excl;
}

// pass 1: block-chunked multisplit. Each block histograms ITS chunk, claims one
// contiguous region per bucket, writes 8B packed records via LDS cursors.
// Region written entirely by one block -> ~1x line writeback.
__global__ void pass1_kernel(const int* __restrict__ rows, const int* __restrict__ cols,
                             const float* __restrict__ vals,
                             int* __restrict__ bktCur, int2* __restrict__ staging, int E) {
    __shared__ int cnt[NBUCKETS];
    __shared__ int base[NBUCKETS];
    int tid = threadIdx.x;
    for (int i = tid; i < NBUCKETS; i += blockDim.x) cnt[i] = 0;
    __syncthreads();
    int chunk = (E + gridDim.x - 1) / gridDim.x;
    int s = blockIdx.x * chunk;
    int e = min(E, s + chunk);
    for (int i = s + tid; i < e; i += blockDim.x)
        atomicAdd(&cnt[rows[i] >> BSHIFT], 1);
    __syncthreads();
    for (int i = tid; i < NBUCKETS; i += blockDim.x) {
        int c = cnt[i];
        base[i] = c ? atomicAdd(&bktCur[i], c) : 0;
        cnt[i] = 0;                                 // reuse as in-block cursor
    }
    __syncthreads();
    for (int i = s + tid; i < e; i += blockDim.x) {
        int r = rows[i];
        int b = r >> BSHIFT;
        int pos = base[b] + atomicAdd(&cnt[b], 1);
        // pack: bits 0..16 col, 17..24 localrow; .y = val bits
        staging[pos] = make_int2(cols[i] | ((r & 255) << 17), __float_as_int(vals[i]));
    }
}

// pass 2: one block per bucket. LDS 256-row hist + scan gives rowstart AND exact
// CSR slots (bucket-local LDS cursors). Zero global atomics; ~32KB write window.
__global__ void pass2_kernel(const int* __restrict__ bktStart, const int2* __restrict__ staging,
                             int* __restrict__ rowstart, int2* __restrict__ csr) {
    __shared__ int hist[256];
    __shared__ int sc[256];
    __shared__ int cur[256];
    int b = blockIdx.x, tid = threadIdx.x;
    int s = bktStart[b], e = bktStart[b + 1];
    hist[tid] = 0;
    __syncthreads();
    for (int i = s + tid; i < e; i += blockDim.x)
        atomicAdd(&hist[(staging[i].x >> 17) & 255], 1);
    __syncthreads();
    int v = hist[tid];
    sc[tid] = v;
    __syncthreads();
    for (int off = 1; off < 256; off <<= 1) {
        int t = (tid >= off) ? sc[tid - off] : 0;
        __syncthreads();
        sc[tid] += t;
        __syncthreads();
    }
    int excl = sc[tid] - v;
    rowstart[(b << BSHIFT) + tid] = s + excl;       // covers rows 0..100095
    cur[tid] = excl;
    __syncthreads();
    for (int i = s + tid; i < e; i += blockDim.x) {
        int2 rec = staging[i];
        int lr = (rec.x >> 17) & 255;
        int pos = atomicAdd(&cur[lr], 1);
        csr[s + pos] = make_int2(rec.x & 0x1FFFF, rec.y);
    }
}

// pull SpMM: 16 lanes per row, lanes 0..12 each load one 16B fp16 chunk per edge.
__global__ void gather_mid_kernel(const int* __restrict__ rowstart,
                                  const int2* __restrict__ csr,
                                  const half8_t* __restrict__ x,
                                  half8_t* __restrict__ h) {
    int gid = blockIdx.x * blockDim.x + threadIdx.x;
    int row = gid >> 4, lane = gid & 15;
    if (row >= NODES || lane >= CH) return;
    int s = rowstart[row], e = rowstart[row + 1];
    float acc[8] = {0.f, 0.f, 0.f, 0.f, 0.f, 0.f, 0.f, 0.f};
    int i = s;
    for (; i + 1 < e; i += 2) {
        int2 r0 = csr[i], r1 = csr[i + 1];
        half8_t a = x[(size_t)r0.x * CH + lane];
        half8_t b = x[(size_t)r1.x * CH + lane];
        float v0 = __int_as_float(r0.y), v1 = __int_as_float(r1.y);
        #pragma unroll
        for (int k = 0; k < 8; ++k) acc[k] += v0 * (float)a[k] + v1 * (float)b[k];
    }
    if (i < e) {
        int2 r0 = csr[i];
        half8_t a = x[(size_t)r0.x * CH + lane];
        float v0 = __int_as_float(r0.y);
        #pragma unroll
        for (int k = 0; k < 8; ++k) acc[k] += v0 * (float)a[k];
    }
    half8_t hv;
    #pragma unroll
    for (int k = 0; k < 8; ++k) hv[k] = (_Float16)acc[k];
    h[(size_t)row * CH + lane] = hv;
}

// last layer: fused epilogue out = emb + h1 + h2 + acc (fp32 acc, compact layout)
__global__ void gather_last_kernel(const int* __restrict__ rowstart,
                                   const int2* __restrict__ csr,
                                   const half8_t* __restrict__ x,
                                   const half8_t* __restrict__ h1,
                                   const half8_t* __restrict__ h2,
                                   const float4* __restrict__ emb,
                                   float4* __restrict__ out) {
    int gid = blockIdx.x * blockDim.x + threadIdx.x;
    int row = gid >> 4, lane = gid & 15;
    if (row >= NODES || lane >= CH) return;
    int s = rowstart[row], e = rowstart[row + 1];
    float acc[8] = {0.f, 0.f, 0.f, 0.f, 0.f, 0.f, 0.f, 0.f};
    int i = s;
    for (; i + 1 < e; i += 2) {
        int2 r0 = csr[i], r1 = csr[i + 1];
        half8_t a = x[(size_t)r0.x * CH + lane];
        half8_t b = x[(size_t)r1.x * CH + lane];
        float v0 = __int_as_float(r0.y), v1 = __int_as_float(r1.y);
        #pragma unroll
        for (int k = 0; k < 8; ++k) acc[k] += v0 * (float)a[k] + v1 * (float)b[k];
    }
    if (i < e) {
        int2 r0 = csr[i];
        half8_t a = x[(size_t)r0.x * CH + lane];
        float v0 = __int_as_float(r0.y);
        #pragma unroll
        for (int k = 0; k < 8; ++k) acc[k] += v0 * (float)a[k];
    }
    size_t pidx = (size_t)row * CH + lane;
    half8_t a1 = h1[pidx], a2 = h2[pidx];
    int f4 = row * DIM4 + lane * 2;                  // features lane*8 .. lane*8+7
    float4 o0 = emb[f4];
    o0.x += acc[0] + (float)a1[0] + (float)a2[0];
    o0.y += acc[1] + (float)a1[1] + (float)a2[1];
    o0.z += acc[2] + (float)a1[2] + (float)a2[2];
    o0.w += acc[3] + (float)a1[3] + (float)a2[3];
    out[f4] = o0;
    if (lane < 12) {                                 // lane 12 covers only feats 96..99
        float4 o1 = emb[f4 + 1];
        o1.x += acc[4] + (float)a1[4] + (float)a2[4];
        o1.y += acc[5] + (float)a1[5] + (float)a2[5];
        o1.z += acc[6] + (float)a1[6] + (float)a2[6];
        o1.w += acc[7] + (float)a1[7] + (float)a2[7];
        out[f4 + 1] = o1;
    }
}

extern "C" void kernel_launch(void* const* d_in, const int* in_sizes, int n_in,
                              void* d_out, int out_size, void* d_ws, size_t ws_size,
                              hipStream_t stream) {
    const float* emb  = (const float*)d_in[0];
    const int*   rows = (const int*)  d_in[1];
    const int*   cols = (const int*)  d_in[2];
    const float* vals = (const float*)d_in[3];
    const int E = in_sizes[1];

    const size_t ndp_bytes = (size_t)NODES * 104 * sizeof(_Float16);   // 20.8 MB padded

    char* w = (char*)d_ws;
    half8_t* x0p      = (half8_t*)w;  w += ndp_bytes;
    half8_t* h1p      = (half8_t*)w;  w += ndp_bytes;
    half8_t* h2p      = (half8_t*)w;  w += ndp_bytes;
    int2*    staging  = (int2*)   w;  w += (size_t)E * sizeof(int2);   // 12.8 MB
    int2*    csr      = (int2*)   w;  w += (size_t)E * sizeof(int2);   // 12.8 MB
    int*     rowstart = (int*)    w;  w += (size_t)(NBUCKETS << BSHIFT) * sizeof(int);
    int*     bktCount = (int*)    w;  w += 512 * sizeof(int);
    int*     bktStart = (int*)    w;  w += 512 * sizeof(int);
    int*     bktCur   = (int*)    w;  w += 512 * sizeof(int);
    // total ~88.5 MB

    float4* out = (float4*)d_out;

    // ---- build CSR ----
    hipMemsetAsync(bktCount, 0, NBUCKETS * sizeof(int), stream);
    cvt_pad_kernel<<<(NODES * 26 + 255) / 256, 256, 0, stream>>>((const float4*)emb, (half4_t*)x0p);
    bucket_hist_kernel<<<P1_BLOCKS, 256, 0, stream>>>(rows, bktCount, E);
    bucket_scan_kernel<<<1, 512, 0, stream>>>(bktCount, bktStart, bktCur);
    pass1_kernel<<<P1_BLOCKS, 256, 0, stream>>>(rows, cols, vals, bktCur, staging, E);
    pass2_kernel<<<NBUCKETS, 256, 0, stream>>>(bktStart, staging, rowstart, csr);

    // ---- 3 gather SpMM layers; last one fuses the output combine ----
    const long long threads = (long long)NODES * 16;
    dim3 gGrid((unsigned)((threads + 255) / 256)), gBlock(256);
    gather_mid_kernel<<<gGrid, gBlock, 0, stream>>>(rowstart, csr, x0p, h1p);
    gather_mid_kernel<<<gGrid, gBlock, 0, stream>>>(rowstart, csr, h1p, h2p);
    gather_last_kernel<<<gGrid, gBlock, 0, stream>>>(rowstart, csr, h2p, h1p, h2p,
                                                     (const float4*)emb, out);
}